// Round 2
// baseline (42.846 us; speedup 1.0000x reference)
//
#include <hip/hip_runtime.h>

#define NTHREADS 256

#if defined(__has_builtin)
#if __has_builtin(__builtin_amdgcn_exp2f)
#define EXP2F __builtin_amdgcn_exp2f
#else
#define EXP2F exp2f
#endif
#else
#define EXP2F exp2f
#endif

__device__ __forceinline__ float rfl(float x) {
    return __uint_as_float(__builtin_amdgcn_readfirstlane(__float_as_uint(x)));
}

// a is the raw preactivation; sigmoid = 1/(1+exp(-a)) = 1/(1+exp2(-log2e*a))
__device__ __forceinline__ float sigm(float a) {
    float e = EXP2F(a * -1.442695040888963f);
    return __builtin_amdgcn_rcpf(1.0f + e);
}

__global__ __launch_bounds__(NTHREADS, 4)
void mlp6_fused_kernel(const float* __restrict__ xl,
                       const float* __restrict__ yl,
                       const float* __restrict__ xr,
                       const float* __restrict__ W1, const float* __restrict__ b1,
                       const float* __restrict__ W2, const float* __restrict__ b2,
                       const float* __restrict__ W3_2, const float* __restrict__ b3_2,
                       const float* __restrict__ W3_1, const float* __restrict__ b3_1,
                       const float* __restrict__ W4, const float* __restrict__ b4,
                       float* __restrict__ out, int B)
{
    const int tid = threadIdx.x;
    const long long nq = (long long)(B >> 2);          // groups of 4 samples
    long long gq = (long long)blockIdx.x * NTHREADS + tid;
    if (gq >= nq) gq = nq - 1;                         // dup-writes are identical

    // --- vector-load 4 consecutive samples (20 floats = 5 float4) per array ---
    float bl[20], by[20], br_[20];
    {
        const float4* a4 = (const float4*)xl;
        const float4* y4 = (const float4*)yl;
        const float4* c4 = (const float4*)xr;
        long long p = gq * 5;
        #pragma unroll
        for (int q = 0; q < 5; q++) {
            ((float4*)bl)[q]  = a4[p + q];
            ((float4*)by)[q]  = y4[p + q];
            ((float4*)br_)[q] = c4[p + q];
        }
    }

    // --- fold fc3(+fc4) into per-branch 4-vector fw + output bias fbv ---
    // Uniform values; pin to SGPRs via readfirstlane.
    // W3_2 flat [4][2][4] rows j=0..3 <-> branches {0,1,4,5}; W4 flat [2][1][4];
    // W3_1 flat [2][1][4]; b3_2 flat [4][2]; b3_1 flat [2][1]; b4 flat [2][1].
    float fw[6][4];
    #pragma unroll
    for (int h = 0; h < 4; h++) {
        fw[0][h] = rfl(fmaf(W4[1], W3_2[4 + h],  W4[0] * W3_2[h]));
        fw[1][h] = rfl(fmaf(W4[5], W3_2[12 + h], W4[4] * W3_2[8 + h]));
        fw[2][h] = rfl(W3_1[h]);
        fw[3][h] = rfl(W3_1[4 + h]);
        fw[4][h] = rfl(fmaf(W4[3], W3_2[20 + h], W4[2] * W3_2[16 + h]));
        fw[5][h] = rfl(fmaf(W4[7], W3_2[28 + h], W4[6] * W3_2[24 + h]));
    }
    float fbv[4];
    fbv[0] = rfl(b3_1[0]);
    fbv[1] = rfl(b3_1[1]);
    fbv[2] = rfl(W4[0]*b3_2[0] + W4[1]*b3_2[1] + W4[2]*b3_2[4] + W4[3]*b3_2[5] + b4[0]);
    fbv[3] = rfl(W4[4]*b3_2[2] + W4[5]*b3_2[3] + W4[6]*b3_2[6] + W4[7]*b3_2[7] + b4[1]);

    float o[4][4];
    #pragma unroll
    for (int s = 0; s < 4; s++) {
        #pragma unroll
        for (int j = 0; j < 4; j++) o[s][j] = fbv[j];
    }

    // --- one branch MLP over 4 samples; weights via uniform (scalar) loads ---
    auto branch = [&](int k, const float* xb, int slot) {
        float h1[4][4];
        #pragma unroll
        for (int h = 0; h < 4; h++) {
            float a[4];
            float bb = b1[k*4 + h];
            #pragma unroll
            for (int s = 0; s < 4; s++) a[s] = bb;
            #pragma unroll
            for (int i = 0; i < 5; i++) {
                float wv = W1[k*20 + h*5 + i];
                #pragma unroll
                for (int s = 0; s < 4; s++) a[s] = fmaf(xb[s*5 + i], wv, a[s]);
            }
            #pragma unroll
            for (int s = 0; s < 4; s++) h1[s][h] = sigm(a[s]);
        }
        float c[4] = {0.f, 0.f, 0.f, 0.f};
        #pragma unroll
        for (int g = 0; g < 4; g++) {
            float a[4];
            float bb = b2[k*4 + g];
            #pragma unroll
            for (int s = 0; s < 4; s++) a[s] = bb;
            #pragma unroll
            for (int h = 0; h < 4; h++) {
                float wv = W2[k*16 + g*4 + h];
                #pragma unroll
                for (int s = 0; s < 4; s++) a[s] = fmaf(h1[s][h], wv, a[s]);
            }
            float fg = fw[k][g];
            #pragma unroll
            for (int s = 0; s < 4; s++) c[s] = fmaf(sigm(a[s]), fg, c[s]);
        }
        #pragma unroll
        for (int s = 0; s < 4; s++) o[s][slot] += c[s];
    };

    // X = stack([xl, yl, xr, yl, xl, yl]); slots: br2->0, br3->1, {br0,br4}->2, {br1,br5}->3
    branch(0, bl, 2);
    branch(4, bl, 2);
    branch(1, by, 3);
    branch(3, by, 1);
    branch(5, by, 3);
    branch(2, br_, 0);

    float4* out4 = (float4*)out;
    #pragma unroll
    for (int s = 0; s < 4; s++) {
        float4 r;
        r.x = o[s][0]; r.y = o[s][1]; r.z = o[s][2]; r.w = o[s][3];
        out4[gq*4 + s] = r;
    }
}

extern "C" void kernel_launch(void* const* d_in, const int* in_sizes, int n_in,
                              void* d_out, int out_size, void* d_ws, size_t ws_size,
                              hipStream_t stream) {
    const float* xl   = (const float*)d_in[0];
    const float* yl   = (const float*)d_in[1];
    const float* xr   = (const float*)d_in[2];
    // d_in[3] = yr — unused by the reference forward
    const float* W1   = (const float*)d_in[4];
    const float* b1   = (const float*)d_in[5];
    const float* W2   = (const float*)d_in[6];
    const float* b2   = (const float*)d_in[7];
    const float* W3_2 = (const float*)d_in[8];
    const float* b3_2 = (const float*)d_in[9];
    const float* W3_1 = (const float*)d_in[10];
    const float* b3_1 = (const float*)d_in[11];
    const float* W4   = (const float*)d_in[12];
    const float* b4   = (const float*)d_in[13];
    float* out = (float*)d_out;

    int B = in_sizes[0] / 5;               // 2,000,000 (divisible by 4)
    long long nq = (long long)B >> 2;
    int blocks = (int)((nq + NTHREADS - 1) / NTHREADS);
    mlp6_fused_kernel<<<blocks, NTHREADS, 0, stream>>>(
        xl, yl, xr, W1, b1, W2, b2, W3_2, b3_2, W3_1, b3_1, W4, b4, out, B);
}